// Round 8
// baseline (3225.198 us; speedup 1.0000x reference)
//
#include <hip/hip_runtime.h>

#define N_NODES   100000
#define N_EDGES   1600000
#define WALK_LEN  16
#define OUT_DIM   8
#define N_PROBES  32

#define SCAN_BLK  256
#define NBLK      ((N_NODES + SCAN_BLK - 1) / SCAN_BLK)   // 391

// ---- LDS byte-counter build parameters ----
#define HB        128                      // histogram blocks
#define SLICE     (N_EDGES / HB)           // 12500 edges per block (exact)
#define NWORDS    (N_NODES / 4)            // 25000 packed uints = 100 KB LDS

// ---- probe-chunked gather parameters ----
#define NCHUNK    16                       // 16 chunks x 2 probes; 0.8 MB state per chunk
#define CBLK      NBLK                     // blocks per chunk (391)

// ---------------- per-block byte-packed histogram (single pass, LDS atomics) ----------------
__global__ void hist_kernel(const int* __restrict__ arr, unsigned char* __restrict__ partial) {
    __shared__ unsigned int cnt[NWORDS];
    int b = blockIdx.x;
    int t = threadIdx.x;                   // 1024 threads
    for (int i = t; i < NWORDS; i += 1024) cnt[i] = 0;
    __syncthreads();
    const int* a = arr + b * SLICE;
    for (int i = t; i < SLICE; i += 1024) {
        int v = a[i];
        atomicAdd(&cnt[v >> 2], 1u << ((v & 3) * 8));
    }
    __syncthreads();
    unsigned int* dst = (unsigned int*)(partial + (size_t)b * N_NODES);
    for (int i = t; i < NWORDS; i += 1024) dst[i] = cnt[i];
}

// ---------------- outdeg = byte-sum over blocks; emit 1/max(outdeg,1) ----------------
__global__ void reduce_out_kernel(const unsigned char* __restrict__ partial,
                                  float* __restrict__ inv_outdeg) {
    int q = blockIdx.x * blockDim.x + threadIdx.x;   // word index, [0, NWORDS)
    if (q >= NWORDS) return;
    int s0 = 0, s1 = 0, s2 = 0, s3 = 0;
    for (int b = 0; b < HB; b++) {
        unsigned int w = *(const unsigned int*)(partial + (size_t)b * N_NODES + q * 4);
        s0 += w & 0xFF; s1 += (w >> 8) & 0xFF; s2 += (w >> 16) & 0xFF; s3 += (w >> 24) & 0xFF;
    }
    int n = q * 4;
    inv_outdeg[n + 0] = 1.0f / (float)(s0 > 0 ? s0 : 1);
    inv_outdeg[n + 1] = 1.0f / (float)(s1 > 0 ? s1 : 1);
    inv_outdeg[n + 2] = 1.0f / (float)(s2 > 0 ? s2 : 1);
    inv_outdeg[n + 3] = 1.0f / (float)(s3 > 0 ? s3 : 1);
}

// ---------------- indeg = byte-sum; overwrite partial with exclusive prefix over blocks ----------------
__global__ void reduce_scan_col_kernel(unsigned char* __restrict__ partial,
                                       int* __restrict__ indeg) {
    int q = blockIdx.x * blockDim.x + threadIdx.x;   // word index, [0, NWORDS)
    if (q >= NWORDS) return;
    unsigned int r0 = 0, r1 = 0, r2 = 0, r3 = 0;     // running prefixes (fit in a byte)
    for (int b = 0; b < HB; b++) {
        unsigned int* p = (unsigned int*)(partial + (size_t)b * N_NODES + q * 4);
        unsigned int w = *p;
        *p = (r0 & 0xFF) | ((r1 & 0xFF) << 8) | ((r2 & 0xFF) << 16) | ((r3 & 0xFF) << 24);
        r0 += w & 0xFF; r1 += (w >> 8) & 0xFF; r2 += (w >> 16) & 0xFF; r3 += (w >> 24) & 0xFF;
    }
    int n = q * 4;
    indeg[n + 0] = (int)r0;
    indeg[n + 1] = (int)r1;
    indeg[n + 2] = (int)r2;
    indeg[n + 3] = (int)r3;
}

// ---------------- prefix scan of indeg -> offs (exclusive) ----------------
__global__ void scan1_kernel(const int* __restrict__ indeg, int* __restrict__ bsum) {
    __shared__ int s[SCAN_BLK];
    int i = blockIdx.x * SCAN_BLK + threadIdx.x;
    s[threadIdx.x] = (i < N_NODES) ? indeg[i] : 0;
    __syncthreads();
    for (int o = SCAN_BLK / 2; o > 0; o >>= 1) {
        if (threadIdx.x < o) s[threadIdx.x] += s[threadIdx.x + o];
        __syncthreads();
    }
    if (threadIdx.x == 0) bsum[blockIdx.x] = s[0];
}

__global__ void scan2_kernel(int* __restrict__ bsum) {   // single block of 512
    __shared__ int s[512];
    int t = threadIdx.x;
    s[t] = (t < NBLK) ? bsum[t] : 0;
    __syncthreads();
    for (int o = 1; o < 512; o <<= 1) {
        int v = (t >= o) ? s[t - o] : 0;
        __syncthreads();
        s[t] += v;
        __syncthreads();
    }
    if (t < NBLK) bsum[t] = (t == 0) ? 0 : s[t - 1];     // exclusive
}

__global__ void scan3_kernel(const int* __restrict__ indeg, const int* __restrict__ bsum,
                             int* __restrict__ offs) {
    __shared__ int s[SCAN_BLK];
    int t = threadIdx.x;
    int i = blockIdx.x * SCAN_BLK + t;
    int v = (i < N_NODES) ? indeg[i] : 0;
    s[t] = v;
    __syncthreads();
    for (int o = 1; o < SCAN_BLK; o <<= 1) {
        int u = (t >= o) ? s[t - o] : 0;
        __syncthreads();
        s[t] += u;
        __syncthreads();
    }
    if (i < N_NODES) offs[i] = bsum[blockIdx.x] + s[t] - v;   // exclusive
}

// ---------------- CSC fill: LDS byte rank counters seeded with prefix base ----------------
__global__ void place_kernel(const int* __restrict__ row, const int* __restrict__ col,
                             const int* __restrict__ offs,
                             const unsigned char* __restrict__ pbase,
                             int* __restrict__ csc_row) {
    __shared__ unsigned int cnt[NWORDS];
    int b = blockIdx.x;
    int t = threadIdx.x;                   // 1024 threads
    const unsigned int* src = (const unsigned int*)(pbase + (size_t)b * N_NODES);
    for (int i = t; i < NWORDS; i += 1024) cnt[i] = src[i];   // seed with prefix-base bytes
    __syncthreads();
    for (int i = t; i < SLICE; i += 1024) {
        int e = b * SLICE + i;
        int c = col[e];
        int sh = (c & 3) * 8;
        unsigned int old = atomicAdd(&cnt[c >> 2], 1u << sh);
        int pos = (int)((old >> sh) & 0xFF);               // prefix-base + in-block rank
        csc_row[offs[c] + pos] = row[e];
    }
}

// ---------------- s0 (chunk-major float2, pre-scaled) + probes_t (chunk-major) ----------------
// layout: buf[((c*N + n)*2 + i)] = probes[n*32 + c*2 + i]
__global__ void s0_kernel(const float* __restrict__ probes, const float* __restrict__ inv_outdeg,
                          float* __restrict__ s0, float* __restrict__ probes_t) {
    int gid = blockIdx.x * blockDim.x + threadIdx.x;   // [0, N*32)
    int n = gid >> 5;
    int p = gid & 31;
    int c = p >> 1;
    int i = p & 1;
    float v = probes[gid];
    size_t idx = ((size_t)c * N_NODES + n) * 2 + i;
    probes_t[idx] = v;
    s0[idx] = v * inv_outdeg[n];
}

// ---------------- out[n][j] = b[j] ----------------
__global__ void init_out_kernel(const float* __restrict__ b, float* __restrict__ out) {
    int gid = blockIdx.x * blockDim.x + threadIdx.x;   // [0, N*8) exact
    out[gid] = b[gid & 7];
}

// ---------------- probe-chunked gather + rescale + partial diag + out-accumulate ----------------
// grid: chunk-major (chunk = blockIdx.x / CBLK). One thread per (chunk, node).
// LDS pad (24 KB) limits to 6 blocks/CU so the in-flight block window spans ~4 chunks
// (~3.2 MB of state) -> gathers hit per-XCD L2 instead of the cross-XCD fabric.
__global__ __launch_bounds__(256) void gather_kernel(
        const int* __restrict__ offs, const int* __restrict__ indeg,
        const int* __restrict__ csc_row,
        const float2* __restrict__ s_cur, const float2* __restrict__ probes_t,
        const float* __restrict__ inv_outdeg,
        float2* __restrict__ s_new,
        float* __restrict__ pd_cur, const float* __restrict__ pd_prev,
        const float* __restrict__ W, float* __restrict__ out, int k) {
    volatile __shared__ int lds_pad[6144];             // 24 KB occupancy limiter
    lds_pad[threadIdx.x & 63] = 0;

    int bid = blockIdx.x;
    int c = bid / CBLK;
    int n = (bid - c * CBLK) * 256 + threadIdx.x;
    if (n >= N_NODES) return;

    int start = offs[n];
    int cnt   = indeg[n];
    const float2* src = s_cur + (size_t)c * N_NODES;
    float ax = 0.f, ay = 0.f;
    int q = 0;
    for (; q + 4 <= cnt; q += 4) {
        int r0 = __builtin_nontemporal_load(&csc_row[start + q + 0]);
        int r1 = __builtin_nontemporal_load(&csc_row[start + q + 1]);
        int r2 = __builtin_nontemporal_load(&csc_row[start + q + 2]);
        int r3 = __builtin_nontemporal_load(&csc_row[start + q + 3]);
        float2 v0 = src[r0];
        float2 v1 = src[r1];
        float2 v2 = src[r2];
        float2 v3 = src[r3];
        ax += v0.x + v1.x + v2.x + v3.x;
        ay += v0.y + v1.y + v2.y + v3.y;
    }
    for (; q < cnt; q++) {
        int r = csc_row[start + q];
        float2 v = src[r];
        ax += v.x; ay += v.y;
    }

    float inv = inv_outdeg[n];
    size_t cn = (size_t)c * N_NODES + n;
    s_new[cn] = make_float2(ax * inv, ay * inv);       // pre-scaled state for next step
    float2 pr = probes_t[cn];
    pd_cur[cn] = ax * pr.x + ay * pr.y;                // partial Hutchinson dot (2 probes)

    // chunk-0 blocks run first: reduce previous step's partials and accumulate output
    if (c == 0 && k > 0) {
        float s = 0.f;
#pragma unroll
        for (int cc = 0; cc < NCHUNK; cc++) s += pd_prev[(size_t)cc * N_NODES + n];
        s *= (1.0f / (float)N_PROBES);
        float* o = out + (size_t)n * OUT_DIM;
#pragma unroll
        for (int j = 0; j < OUT_DIM; j++) o[j] += s * W[j * WALK_LEN + (k - 1)];
    }
}

// ---------------- final step's diag -> out ----------------
__global__ void finish_kernel(const float* __restrict__ pd_last, const float* __restrict__ W,
                              float* __restrict__ out) {
    int n = blockIdx.x * blockDim.x + threadIdx.x;
    if (n >= N_NODES) return;
    float s = 0.f;
#pragma unroll
    for (int cc = 0; cc < NCHUNK; cc++) s += pd_last[(size_t)cc * N_NODES + n];
    s *= (1.0f / (float)N_PROBES);
    float* o = out + (size_t)n * OUT_DIM;
#pragma unroll
    for (int j = 0; j < OUT_DIM; j++) o[j] += s * W[j * WALK_LEN + (WALK_LEN - 1)];
}

extern "C" void kernel_launch(void* const* d_in, const int* in_sizes, int n_in,
                              void* d_out, int out_size, void* d_ws, size_t ws_size,
                              hipStream_t stream) {
    const int*   edge_index = (const int*)d_in[0];
    const int*   row    = edge_index;
    const int*   col    = edge_index + N_EDGES;
    const float* probes = (const float*)d_in[2];
    const float* W      = (const float*)d_in[3];
    const float* b      = (const float*)d_in[4];
    float*       out    = (float*)d_out;

    // workspace carve-up (256B aligned), total ~58.9 MB
    char* ws = (char*)d_ws;
    size_t off = 0;
    auto carve = [&](size_t bytes) -> void* {
        void* p = ws + off;
        off += (bytes + 255) & ~(size_t)255;
        return p;
    };
    int*           indeg   = (int*)          carve((size_t)N_NODES * 4);            // 400 KB
    int*           offs    = (int*)          carve((size_t)N_NODES * 4);            // 400 KB
    float*         inv_od  = (float*)        carve((size_t)N_NODES * 4);            // 400 KB
    int*           bsum    = (int*)          carve((size_t)NBLK * 4);               // ~1.6 KB
    unsigned char* partial = (unsigned char*)carve((size_t)HB * N_NODES);           // 12.8 MB
    int*           csc_row = (int*)          carve((size_t)N_EDGES * 4);            // 6.4 MB
    float*         bufA    = (float*)        carve((size_t)N_NODES * N_PROBES * 4); // 12.8 MB
    float*         bufB    = (float*)        carve((size_t)N_NODES * N_PROBES * 4); // 12.8 MB
    float*         pd0     = (float*)        carve((size_t)NCHUNK * N_NODES * 4);   // 6.4 MB
    float*         pd1     = (float*)        carve((size_t)NCHUNK * N_NODES * 4);   // 6.4 MB
    // probes_t reuses the partial-histogram region (dead after place_kernel)
    float*         probes_t = (float*)partial;                                      // 12.8 MB

    const int B = 256;
    // ---- build CSC + inv_outdeg (zero global atomics) ----
    hist_kernel<<<HB, 1024, 0, stream>>>(row, partial);
    reduce_out_kernel<<<(NWORDS + B - 1) / B, B, 0, stream>>>(partial, inv_od);
    hist_kernel<<<HB, 1024, 0, stream>>>(col, partial);
    reduce_scan_col_kernel<<<(NWORDS + B - 1) / B, B, 0, stream>>>(partial, indeg);
    scan1_kernel<<<NBLK, SCAN_BLK, 0, stream>>>(indeg, bsum);
    scan2_kernel<<<1, 512, 0, stream>>>(bsum);
    scan3_kernel<<<NBLK, SCAN_BLK, 0, stream>>>(indeg, bsum, offs);
    place_kernel<<<HB, 1024, 0, stream>>>(row, col, offs, partial, csc_row);

    // ---- transposed (chunk-major) s0 and probes; init out with bias ----
    s0_kernel<<<(N_NODES * N_PROBES) / B, B, 0, stream>>>(probes, inv_od, bufB, probes_t);
    init_out_kernel<<<(N_NODES * OUT_DIM) / B, B, 0, stream>>>(b, out);

    // ---- 16 chunk-phased transition steps ----
    const float* cur = bufB;   // s_0 (chunk-major)
    for (int k = 0; k < WALK_LEN; k++) {
        float* nxt     = (k & 1) ? bufB : bufA;
        float* pd_cur  = (k & 1) ? pd1 : pd0;
        float* pd_prev = (k & 1) ? pd0 : pd1;
        gather_kernel<<<NCHUNK * CBLK, 256, 0, stream>>>(
            offs, indeg, csc_row, (const float2*)cur, (const float2*)probes_t,
            inv_od, (float2*)nxt, pd_cur, pd_prev, W, out, k);
        cur = nxt;
    }

    // ---- fold final step's diag into out ----
    finish_kernel<<<NBLK, B, 0, stream>>>(pd1, W, out);
}

// Round 9
// 667.570 us; speedup vs baseline: 4.8313x; 4.8313x over previous
//
#include <hip/hip_runtime.h>

#define N_NODES   100000
#define N_EDGES   1600000
#define WALK_LEN  16
#define OUT_DIM   8
#define N_PROBES  32

#define SCAN_BLK  256
#define NBLK      ((N_NODES + SCAN_BLK - 1) / SCAN_BLK)   // 391

// ---- LDS byte-counter build parameters ----
#define HB        128                      // histogram blocks
#define SLICE     (N_EDGES / HB)           // 12500 edges per block (exact)
#define NWORDS    (N_NODES / 4)            // 25000 packed uints = 100 KB LDS

// ---------------- per-block byte-packed histogram (single pass, LDS atomics) ----------------
__global__ void hist_kernel(const int* __restrict__ arr, unsigned char* __restrict__ partial) {
    __shared__ unsigned int cnt[NWORDS];
    int b = blockIdx.x;
    int t = threadIdx.x;                   // 1024 threads
    for (int i = t; i < NWORDS; i += 1024) cnt[i] = 0;
    __syncthreads();
    const int* a = arr + b * SLICE;
    for (int i = t; i < SLICE; i += 1024) {
        int v = a[i];
        atomicAdd(&cnt[v >> 2], 1u << ((v & 3) * 8));
    }
    __syncthreads();
    unsigned int* dst = (unsigned int*)(partial + (size_t)b * N_NODES);
    for (int i = t; i < NWORDS; i += 1024) dst[i] = cnt[i];
}

// ---------------- outdeg = byte-sum over blocks; emit 1/max(outdeg,1) ----------------
__global__ void reduce_out_kernel(const unsigned char* __restrict__ partial,
                                  float* __restrict__ inv_outdeg) {
    int q = blockIdx.x * blockDim.x + threadIdx.x;   // word index, [0, NWORDS)
    if (q >= NWORDS) return;
    int s0 = 0, s1 = 0, s2 = 0, s3 = 0;
    for (int b = 0; b < HB; b++) {
        unsigned int w = *(const unsigned int*)(partial + (size_t)b * N_NODES + q * 4);
        s0 += w & 0xFF; s1 += (w >> 8) & 0xFF; s2 += (w >> 16) & 0xFF; s3 += (w >> 24) & 0xFF;
    }
    int n = q * 4;
    inv_outdeg[n + 0] = 1.0f / (float)(s0 > 0 ? s0 : 1);
    inv_outdeg[n + 1] = 1.0f / (float)(s1 > 0 ? s1 : 1);
    inv_outdeg[n + 2] = 1.0f / (float)(s2 > 0 ? s2 : 1);
    inv_outdeg[n + 3] = 1.0f / (float)(s3 > 0 ? s3 : 1);
}

// ---------------- indeg = byte-sum; overwrite partial with exclusive prefix over blocks ----------------
__global__ void reduce_scan_col_kernel(unsigned char* __restrict__ partial,
                                       int* __restrict__ indeg) {
    int q = blockIdx.x * blockDim.x + threadIdx.x;   // word index, [0, NWORDS)
    if (q >= NWORDS) return;
    unsigned int r0 = 0, r1 = 0, r2 = 0, r3 = 0;     // running prefixes (fit in a byte)
    for (int b = 0; b < HB; b++) {
        unsigned int* p = (unsigned int*)(partial + (size_t)b * N_NODES + q * 4);
        unsigned int w = *p;
        *p = (r0 & 0xFF) | ((r1 & 0xFF) << 8) | ((r2 & 0xFF) << 16) | ((r3 & 0xFF) << 24);
        r0 += w & 0xFF; r1 += (w >> 8) & 0xFF; r2 += (w >> 16) & 0xFF; r3 += (w >> 24) & 0xFF;
    }
    int n = q * 4;
    indeg[n + 0] = (int)r0;
    indeg[n + 1] = (int)r1;
    indeg[n + 2] = (int)r2;
    indeg[n + 3] = (int)r3;
}

// ---------------- prefix scan of indeg -> offs (exclusive) ----------------
__global__ void scan1_kernel(const int* __restrict__ indeg, int* __restrict__ bsum) {
    __shared__ int s[SCAN_BLK];
    int i = blockIdx.x * SCAN_BLK + threadIdx.x;
    s[threadIdx.x] = (i < N_NODES) ? indeg[i] : 0;
    __syncthreads();
    for (int o = SCAN_BLK / 2; o > 0; o >>= 1) {
        if (threadIdx.x < o) s[threadIdx.x] += s[threadIdx.x + o];
        __syncthreads();
    }
    if (threadIdx.x == 0) bsum[blockIdx.x] = s[0];
}

__global__ void scan2_kernel(int* __restrict__ bsum) {   // single block of 512
    __shared__ int s[512];
    int t = threadIdx.x;
    s[t] = (t < NBLK) ? bsum[t] : 0;
    __syncthreads();
    for (int o = 1; o < 512; o <<= 1) {
        int v = (t >= o) ? s[t - o] : 0;
        __syncthreads();
        s[t] += v;
        __syncthreads();
    }
    if (t < NBLK) bsum[t] = (t == 0) ? 0 : s[t - 1];     // exclusive
}

__global__ void scan3_kernel(const int* __restrict__ indeg, const int* __restrict__ bsum,
                             int* __restrict__ offs) {
    __shared__ int s[SCAN_BLK];
    int t = threadIdx.x;
    int i = blockIdx.x * SCAN_BLK + t;
    int v = (i < N_NODES) ? indeg[i] : 0;
    s[t] = v;
    __syncthreads();
    for (int o = 1; o < SCAN_BLK; o <<= 1) {
        int u = (t >= o) ? s[t - o] : 0;
        __syncthreads();
        s[t] += u;
        __syncthreads();
    }
    if (i < N_NODES) offs[i] = bsum[blockIdx.x] + s[t] - v;   // exclusive
}

// ---------------- CSC fill: LDS byte rank counters seeded with prefix base ----------------
__global__ void place_kernel(const int* __restrict__ row, const int* __restrict__ col,
                             const int* __restrict__ offs,
                             const unsigned char* __restrict__ pbase,
                             int* __restrict__ csc_row) {
    __shared__ unsigned int cnt[NWORDS];
    int b = blockIdx.x;
    int t = threadIdx.x;                   // 1024 threads
    const unsigned int* src = (const unsigned int*)(pbase + (size_t)b * N_NODES);
    for (int i = t; i < NWORDS; i += 1024) cnt[i] = src[i];   // seed with prefix-base bytes
    __syncthreads();
    for (int i = t; i < SLICE; i += 1024) {
        int e = b * SLICE + i;
        int c = col[e];
        int sh = (c & 3) * 8;
        unsigned int old = atomicAdd(&cnt[c >> 2], 1u << sh);
        int pos = (int)((old >> sh) & 0xFF);               // prefix-base + in-block rank
        csc_row[offs[c] + pos] = row[e];
    }
}

// ---------------- s0 = probes * inv_outdeg ----------------
__global__ void s0_kernel(const float* __restrict__ probes, const float* __restrict__ inv_outdeg,
                          float* __restrict__ s0) {
    int gid = blockIdx.x * blockDim.x + threadIdx.x;   // [0, N*32)
    s0[gid] = probes[gid] * inv_outdeg[gid >> 5];
}

// ---------------- fused unweighted gather + rescale + Hutchinson diag ----------------
// 8 threads per node; thread (n, j) owns probes [4j, 4j+4) -> the 8 lanes of one node
// together read exactly one 128B line per edge (full line utilization).
// Burst-16 pipeline: 16 index loads then 16 independent float4 gathers in flight
// (MLP-bound -> BW-bound transition).
__global__ void gather_kernel(const int* __restrict__ offs, const int* __restrict__ indeg,
                              const int* __restrict__ csc_row,
                              const float* __restrict__ s_cur, const float* __restrict__ probes,
                              const float* __restrict__ inv_outdeg,
                              float* __restrict__ s_new, float* __restrict__ diag_row) {
    int gid = blockIdx.x * blockDim.x + threadIdx.x;   // [0, N*8) exact
    int n = gid >> 3;
    int j = (gid & 7) << 2;
    int start = offs[n];
    int cnt   = indeg[n];
    float inv = inv_outdeg[n];
    float4 acc = make_float4(0.f, 0.f, 0.f, 0.f);
    int q = 0;
    for (; q + 16 <= cnt; q += 16) {
        int r[16];
#pragma unroll
        for (int u = 0; u < 16; u++) r[u] = csc_row[start + q + u];
        float4 v[16];
#pragma unroll
        for (int u = 0; u < 16; u++)
            v[u] = *reinterpret_cast<const float4*>(s_cur + (size_t)r[u] * N_PROBES + j);
#pragma unroll
        for (int u = 0; u < 16; u++) {
            acc.x += v[u].x; acc.y += v[u].y; acc.z += v[u].z; acc.w += v[u].w;
        }
    }
    for (; q + 4 <= cnt; q += 4) {
        int r[4];
#pragma unroll
        for (int u = 0; u < 4; u++) r[u] = csc_row[start + q + u];
        float4 v[4];
#pragma unroll
        for (int u = 0; u < 4; u++)
            v[u] = *reinterpret_cast<const float4*>(s_cur + (size_t)r[u] * N_PROBES + j);
#pragma unroll
        for (int u = 0; u < 4; u++) {
            acc.x += v[u].x; acc.y += v[u].y; acc.z += v[u].z; acc.w += v[u].w;
        }
    }
    for (; q < cnt; q++) {
        int r = csc_row[start + q];
        const float4 v = *reinterpret_cast<const float4*>(s_cur + (size_t)r * N_PROBES + j);
        acc.x += v.x; acc.y += v.y; acc.z += v.z; acc.w += v.w;
    }
    // acc = P_k[n] fragment (true probe vector). Write pre-scaled for next step.
    float4 sv = make_float4(acc.x * inv, acc.y * inv, acc.z * inv, acc.w * inv);
    *reinterpret_cast<float4*>(s_new + (size_t)n * N_PROBES + j) = sv;
    const float4 pr = *reinterpret_cast<const float4*>(probes + (size_t)n * N_PROBES + j);
    float dot = acc.x * pr.x + acc.y * pr.y + acc.z * pr.z + acc.w * pr.w;
    dot += __shfl_xor(dot, 4, 8);
    dot += __shfl_xor(dot, 2, 8);
    dot += __shfl_xor(dot, 1, 8);
    if ((gid & 7) == 0) diag_row[n] = dot * (1.0f / (float)N_PROBES);
}

// ---------------- out[n] = diags[n,:] @ W^T + b ----------------
__global__ void out_kernel(const float* __restrict__ diags, const float* __restrict__ W,
                           const float* __restrict__ b, float* __restrict__ out) {
    int n = blockIdx.x * blockDim.x + threadIdx.x;
    if (n >= N_NODES) return;
    float d[WALK_LEN];
#pragma unroll
    for (int k = 0; k < WALK_LEN; k++) d[k] = diags[(size_t)k * N_NODES + n];
    float o[OUT_DIM];
#pragma unroll
    for (int j = 0; j < OUT_DIM; j++) {
        float acc = b[j];
#pragma unroll
        for (int k = 0; k < WALK_LEN; k++) acc += d[k] * W[j * WALK_LEN + k];
        o[j] = acc;
    }
    float4* outp = reinterpret_cast<float4*>(out + (size_t)n * OUT_DIM);
    outp[0] = make_float4(o[0], o[1], o[2], o[3]);
    outp[1] = make_float4(o[4], o[5], o[6], o[7]);
}

extern "C" void kernel_launch(void* const* d_in, const int* in_sizes, int n_in,
                              void* d_out, int out_size, void* d_ws, size_t ws_size,
                              hipStream_t stream) {
    const int*   edge_index = (const int*)d_in[0];
    const int*   row    = edge_index;
    const int*   col    = edge_index + N_EDGES;
    const float* probes = (const float*)d_in[2];
    const float* W      = (const float*)d_in[3];
    const float* b      = (const float*)d_in[4];
    float*       out    = (float*)d_out;

    // workspace carve-up (256B aligned)
    char* ws = (char*)d_ws;
    size_t off = 0;
    auto carve = [&](size_t bytes) -> void* {
        void* p = ws + off;
        off += (bytes + 255) & ~(size_t)255;
        return p;
    };
    int*           indeg   = (int*)          carve((size_t)N_NODES * 4);            // 400 KB
    int*           offs    = (int*)          carve((size_t)N_NODES * 4);            // 400 KB
    float*         inv_od  = (float*)        carve((size_t)N_NODES * 4);            // 400 KB
    int*           bsum    = (int*)          carve((size_t)NBLK * 4);               // ~1.6 KB
    unsigned char* partial = (unsigned char*)carve((size_t)HB * N_NODES);           // 12.8 MB
    int*           csc_row = (int*)          carve((size_t)N_EDGES * 4);            // 6.4 MB
    float*         bufA    = (float*)        carve((size_t)N_NODES * N_PROBES * 4); // 12.8 MB
    float*         bufB    = (float*)        carve((size_t)N_NODES * N_PROBES * 4); // 12.8 MB
    float*         diags   = (float*)        carve((size_t)WALK_LEN * N_NODES * 4); // 6.4 MB

    const int B = 256;
    // ---- build CSC + inv_outdeg, zero global atomics, single pass per histogram ----
    hist_kernel<<<HB, 1024, 0, stream>>>(row, partial);
    reduce_out_kernel<<<(NWORDS + B - 1) / B, B, 0, stream>>>(partial, inv_od);
    hist_kernel<<<HB, 1024, 0, stream>>>(col, partial);
    reduce_scan_col_kernel<<<(NWORDS + B - 1) / B, B, 0, stream>>>(partial, indeg);
    scan1_kernel<<<NBLK, SCAN_BLK, 0, stream>>>(indeg, bsum);
    scan2_kernel<<<1, 512, 0, stream>>>(bsum);
    scan3_kernel<<<NBLK, SCAN_BLK, 0, stream>>>(indeg, bsum, offs);
    place_kernel<<<HB, 1024, 0, stream>>>(row, col, offs, partial, csc_row);

    // ---- s0 = probes * inv_outdeg ----
    s0_kernel<<<(N_NODES * N_PROBES) / B, B, 0, stream>>>(probes, inv_od, bufB);

    // ---- 16 fused transition + diag steps (no atomics) ----
    const float* cur = bufB;   // s_0
    for (int k = 0; k < WALK_LEN; k++) {
        float* nxt = (k & 1) ? bufB : bufA;
        gather_kernel<<<(N_NODES * 8 + B - 1) / B, B, 0, stream>>>(
            offs, indeg, csc_row, cur, probes, inv_od, nxt, diags + (size_t)k * N_NODES);
        cur = nxt;
    }

    out_kernel<<<(N_NODES + B - 1) / B, B, 0, stream>>>(diags, W, b, out);
}